// Round 12
// baseline (60.356 us; speedup 1.0000x reference)
//
#include <hip/hip_runtime.h>

#define BB 32
#define FF 8
#define NN 131072
#define CC 16

#define CHUNKS 64
#define POINTS (NN / CHUNKS)   // 2048
#define NBLK   (CHUNKS * BB)   // 2048

constexpr float DELTA_VAR  = 0.5f;
constexpr float DELTA_DIST = 1.5f;
constexpr float ALPHA = 1.0f, BETA = 1.0f, GAMMA = 0.001f;

// ws float layout — every slot is written before it is read each launch;
// no zeroing, no atomics anywhere in the pipeline.
#define PSLOT    160                       // 144 used, padded
#define WS_PART  0                         // NBLK*PSLOT
#define WS_VARP  (NBLK * PSLOT)            // NBLK var partials (plain stores)
#define WS_DRG   (WS_VARP + NBLK)          // 32 per-batch dist+reg (plain stores)

// ---------------- Pass 1: dual-pipe per-chunk sums + counts -----------------
// Waves 0-1 (features 0-3): LDS private-row RMW (R10-proven).
// Waves 2-3 (features 4-7): 16 VGPR accumulators via unrolled compare-select
// (VALU pipe, idle until now), one-shot LDS dump at the end.
// Both pipes run concurrently on each CU (m114); LDS hot-loop traffic halves.
__global__ __launch_bounds__(256) void k_sums(const float* __restrict__ x,
                                              const int* __restrict__ tgt,
                                              float* __restrict__ ws) {
    __shared__ float priv[128 * 17];   // 8.7 KB LDS-path rows (f 0..3)
    __shared__ float dmp[128 * 17];    // 8.7 KB register-path dump (f 4..7)
    __shared__ float cpriv[32 * 17];   // 2.2 KB counts (f==0 group)
    const int tid = threadIdx.x;
    if (tid < 128) {
#pragma unroll
        for (int i = 0; i < 16; ++i) priv[tid * 17 + i] = 0.f;
    }
    if (tid < 32) {
#pragma unroll
        for (int i = 0; i < 16; ++i) cpriv[tid * 17 + i] = 0.f;
    }
    __syncthreads();

    const int b  = blockIdx.y;
    const int ch = blockIdx.x;
    const int n0 = ch * POINTS;
    const int*   __restrict__ tb = tgt + (size_t)b * NN;

    if (tid < 128) {
        // ---- LDS path: feature f = tid>>5 in 0..3 (waves 0-1) ----
        const int f = tid >> 5;
        const int g = tid & 31;
        const float* __restrict__ xf = x + (size_t)b * FF * NN + (size_t)f * NN;
        const int base  = tid * 17;
        const int cbase = g * 17;
#pragma unroll 2
        for (int k = 0; k < POINTS / 128; ++k) {
            const int n = n0 + k * 128 + g * 4;
            const int4   t4 = *reinterpret_cast<const int4*>(tb + n);
            const float4 v  = *reinterpret_cast<const float4*>(xf + n);
            priv[base + t4.x] += v.x;
            priv[base + t4.y] += v.y;
            priv[base + t4.z] += v.z;
            priv[base + t4.w] += v.w;
            if (f == 0) {
                cpriv[cbase + t4.x] += 1.f;
                cpriv[cbase + t4.y] += 1.f;
                cpriv[cbase + t4.z] += 1.f;
                cpriv[cbase + t4.w] += 1.f;
            }
        }
    } else {
        // ---- VALU path: feature f = 4 + ((tid-128)>>5) (waves 2-3) ----
        const int r = tid - 128;
        const int f = 4 + (r >> 5);
        const int g = r & 31;
        const float* __restrict__ xf = x + (size_t)b * FF * NN + (size_t)f * NN;
        float a[CC];
#pragma unroll
        for (int c = 0; c < CC; ++c) a[c] = 0.f;
#pragma unroll 2
        for (int k = 0; k < POINTS / 128; ++k) {
            const int n = n0 + k * 128 + g * 4;
            const int4   t4 = *reinterpret_cast<const int4*>(tb + n);
            const float4 v  = *reinterpret_cast<const float4*>(xf + n);
#pragma unroll
            for (int c = 0; c < CC; ++c) {
                a[c] += (t4.x == c) ? v.x : 0.f;
                a[c] += (t4.y == c) ? v.y : 0.f;
                a[c] += (t4.z == c) ? v.z : 0.f;
                a[c] += (t4.w == c) ? v.w : 0.f;
            }
        }
#pragma unroll
        for (int c = 0; c < CC; ++c) dmp[r * 17 + c] = a[c];
    }
    __syncthreads();

    // block reduce -> per-block partial slots (plain stores, no atomics)
    float* const part = &ws[WS_PART + (size_t)(b * CHUNKS + ch) * PSLOT];
    if (tid < 128) {
        const int rf = tid >> 4, rc = tid & 15;   // slot = f*16 + c
        float s = 0.f;
        if (rf < 4) {
#pragma unroll
            for (int gg = 0; gg < 32; ++gg) s += priv[(rf * 32 + gg) * 17 + rc];
        } else {
#pragma unroll
            for (int gg = 0; gg < 32; ++gg) s += dmp[((rf - 4) * 32 + gg) * 17 + rc];
        }
        part[tid] = s;
    } else if (tid < 144) {
        const int rc = tid - 128;
        float s = 0.f;
#pragma unroll
        for (int gg = 0; gg < 32; ++gg) s += cpriv[gg * 17 + rc];
        part[tid] = s;
    }
}

// ---------------- Pass 2: variance term; ch==0 also dist+reg (R10 verbatim) -
__global__ __launch_bounds__(256) void k_var(const float* __restrict__ x,
                                             const int* __restrict__ tgt,
                                             float* __restrict__ ws) {
    __shared__ float sred[144];
    __shared__ float smf[CC * 12];     // float4-pair rows at stride 3 float4s
    __shared__ float sinv[CC];
    __shared__ float wsum[4];
    __shared__ int   sst[CC];

    const int tid = threadIdx.x;
    const int b   = blockIdx.y;
    const int ch  = blockIdx.x;

    // ---- prologue: derive means/inv from the 64 chunk partials ----
    if (tid < 144) {
        const float* p = &ws[WS_PART + (size_t)b * CHUNKS * PSLOT + tid];
        float s = 0.f;
#pragma unroll 16
        for (int c2 = 0; c2 < CHUNKS; ++c2) s += p[(size_t)c2 * PSLOT];
        sred[tid] = s;
    }
    if (ch == 0 && tid >= 144 && tid < 160) sst[tid - 144] = tgt[(size_t)b * NN + (tid - 144)];
    __syncthreads();
    if (tid < CC) {
        const float cnt = sred[128 + tid];
        sinv[tid] = cnt > 0.f ? 1.f / cnt : 0.f;
    }
    __syncthreads();
    if (tid < 128) {
        const int f = tid >> 4, c = tid & 15;
        smf[c * 12 + f] = sred[tid] * sinv[c];
    }
    __syncthreads();

    // ---- main loop: variance term over own chunk ----
    const float4* sm4 = reinterpret_cast<const float4*>(smf);
    const int n0 = ch * POINTS;
    const float* __restrict__ xb = x + (size_t)b * FF * NN;
    const int*   __restrict__ tb = tgt + (size_t)b * NN;

    float acc = 0.f;
#pragma unroll
    for (int it = 0; it < 2; ++it) {
        const int n = n0 + tid * 4 + it * 1024;
        const int4 t4 = *reinterpret_cast<const int4*>(tb + n);
        const float4 A0 = sm4[3 * t4.x], B0 = sm4[3 * t4.x + 1];
        const float4 A1 = sm4[3 * t4.y], B1 = sm4[3 * t4.y + 1];
        const float4 A2 = sm4[3 * t4.z], B2 = sm4[3 * t4.z + 1];
        const float4 A3 = sm4[3 * t4.w], B3 = sm4[3 * t4.w + 1];
        float s0, s1, s2, s3;
        {
            const float4 v = *reinterpret_cast<const float4*>(xb + 0 * NN + n);
            s0 = fabsf(v.x - A0.x); s1 = fabsf(v.y - A1.x);
            s2 = fabsf(v.z - A2.x); s3 = fabsf(v.w - A3.x);
        }
        {
            const float4 v = *reinterpret_cast<const float4*>(xb + 1 * NN + n);
            s0 += fabsf(v.x - A0.y); s1 += fabsf(v.y - A1.y);
            s2 += fabsf(v.z - A2.y); s3 += fabsf(v.w - A3.y);
        }
        {
            const float4 v = *reinterpret_cast<const float4*>(xb + 2 * NN + n);
            s0 += fabsf(v.x - A0.z); s1 += fabsf(v.y - A1.z);
            s2 += fabsf(v.z - A2.z); s3 += fabsf(v.w - A3.z);
        }
        {
            const float4 v = *reinterpret_cast<const float4*>(xb + 3 * NN + n);
            s0 += fabsf(v.x - A0.w); s1 += fabsf(v.y - A1.w);
            s2 += fabsf(v.z - A2.w); s3 += fabsf(v.w - A3.w);
        }
        {
            const float4 v = *reinterpret_cast<const float4*>(xb + 4 * NN + n);
            s0 += fabsf(v.x - B0.x); s1 += fabsf(v.y - B1.x);
            s2 += fabsf(v.z - B2.x); s3 += fabsf(v.w - B3.x);
        }
        {
            const float4 v = *reinterpret_cast<const float4*>(xb + 5 * NN + n);
            s0 += fabsf(v.x - B0.y); s1 += fabsf(v.y - B1.y);
            s2 += fabsf(v.z - B2.y); s3 += fabsf(v.w - B3.y);
        }
        {
            const float4 v = *reinterpret_cast<const float4*>(xb + 6 * NN + n);
            s0 += fabsf(v.x - B0.z); s1 += fabsf(v.y - B1.z);
            s2 += fabsf(v.z - B2.z); s3 += fabsf(v.w - B3.z);
        }
        {
            const float4 v = *reinterpret_cast<const float4*>(xb + 7 * NN + n);
            s0 += fabsf(v.x - B0.w); s1 += fabsf(v.y - B1.w);
            s2 += fabsf(v.z - B2.w); s3 += fabsf(v.w - B3.w);
        }
        float h;
        h = fmaxf(s0 - DELTA_VAR, 0.f); acc += h * h * sinv[t4.x];
        h = fmaxf(s1 - DELTA_VAR, 0.f); acc += h * h * sinv[t4.y];
        h = fmaxf(s2 - DELTA_VAR, 0.f); acc += h * h * sinv[t4.z];
        h = fmaxf(s3 - DELTA_VAR, 0.f); acc += h * h * sinv[t4.w];
    }

#pragma unroll
    for (int off = 32; off > 0; off >>= 1) acc += __shfl_down(acc, off, 64);
    if ((tid & 63) == 0) wsum[tid >> 6] = acc;
    __syncthreads();
    if (tid == 0) ws[WS_VARP + b * CHUNKS + ch] = wsum[0] + wsum[1] + wsum[2] + wsum[3];

    // ---- ch==0 only: dist + reg from OWN means (plain store, no sync) ----
    if (ch == 0 && tid < CC) {
        const int c = tid;
        float l1 = 0.f;
#pragma unroll
        for (int f = 0; f < FF; ++f) l1 += fabsf(smf[c * 12 + f]);
        const int ti = sst[c];
        float mi[FF];
#pragma unroll
        for (int f = 0; f < FF; ++f) mi[f] = smf[ti * 12 + f];
        float dsum = 0.f;
        for (int j = 0; j < CC; ++j) {
            const int tj = sst[j];
            float d = 0.f;
#pragma unroll
            for (int f = 0; f < FF; ++f) d += fabsf(mi[f] - smf[tj * 12 + f]);
            if (j != c) {
                const float h = 2.f * DELTA_DIST - d;
                if (h > 0.f) dsum += h * h;
            }
        }
        float contrib = (GAMMA / (float)(CC * BB)) * l1
                      + (BETA / (float)(CC * (CC - 1) * BB)) * dsum;
#pragma unroll
        for (int off = 8; off > 0; off >>= 1) contrib += __shfl_down(contrib, off, 64);
        if (tid == 0) ws[WS_DRG + b] = contrib;
    }
}

// ---------------- Final: pure reduce of 2048 var partials + 32 drg ----------
__global__ __launch_bounds__(256) void k_final(const float* __restrict__ ws,
                                               float* __restrict__ out) {
    __shared__ float red[4];
    const int tid = threadIdx.x;

    float v = 0.f;
#pragma unroll
    for (int i = 0; i < NBLK / 256; ++i) v += ws[WS_VARP + i * 256 + tid];
    float val = (ALPHA / (float)BB) * v;
    if (tid < BB) val += ws[WS_DRG + tid];

#pragma unroll
    for (int off = 32; off > 0; off >>= 1) val += __shfl_down(val, off, 64);
    if ((tid & 63) == 0) red[tid >> 6] = val;
    __syncthreads();
    if (tid == 0) out[0] = red[0] + red[1] + red[2] + red[3];
}

extern "C" void kernel_launch(void* const* d_in, const int* in_sizes, int n_in,
                              void* d_out, int out_size, void* d_ws, size_t ws_size,
                              hipStream_t stream) {
    const float* x  = (const float*)d_in[0];
    const int* tgt  = (const int*)d_in[1];
    float* out = (float*)d_out;
    float* ws  = (float*)d_ws;

    dim3 grid(CHUNKS, BB);
    k_sums<<<grid, 256, 0, stream>>>(x, tgt, ws);
    k_var <<<grid, 256, 0, stream>>>(x, tgt, ws);
    k_final<<<1, 256, 0, stream>>>(ws, out);
}

// Round 13
// 57.517 us; speedup vs baseline: 1.0494x; 1.0494x over previous
//
#include <hip/hip_runtime.h>

#define BB 32
#define FF 8
#define NN 131072
#define CC 16

#define CHUNKS 64
#define POINTS (NN / CHUNKS)   // 2048
#define NBLK   (CHUNKS * BB)   // 2048

constexpr float DELTA_VAR  = 0.5f;
constexpr float DELTA_DIST = 1.5f;
constexpr float ALPHA = 1.0f, BETA = 1.0f, GAMMA = 0.001f;

// ws float layout — every slot is written before it is read each launch;
// no zeroing, no atomics anywhere in the pipeline.
#define PSLOT    160                       // 144 used, padded
#define WS_PART  0                         // NBLK*PSLOT
#define WS_VARP  (NBLK * PSLOT)            // NBLK var partials (plain stores)
#define WS_DRG   (WS_VARP + NBLK)          // 32 per-batch dist+reg (plain stores)

// ---------------- Pass 1: per-chunk sums + counts (R6/R10-proven verbatim) --
__global__ __launch_bounds__(256) void k_sums(const float* __restrict__ x,
                                              const int* __restrict__ tgt,
                                              float* __restrict__ ws) {
    __shared__ float priv[256 * 17];   // 17.4 KB private rows, stride 17
    __shared__ float cpriv[32 * 17];   //  2.2 KB counts (f==0 group)
    const int tid = threadIdx.x;
#pragma unroll
    for (int i = 0; i < 16; ++i) priv[tid * 17 + i] = 0.f;
    if (tid < 32) {
#pragma unroll
        for (int i = 0; i < 16; ++i) cpriv[tid * 17 + i] = 0.f;
    }
    __syncthreads();

    const int b  = blockIdx.y;
    const int ch = blockIdx.x;
    const int f  = tid >> 5;          // feature group 0..7
    const int g  = tid & 31;          // lane-in-group
    const int n0 = ch * POINTS;
    const float* __restrict__ xf = x + (size_t)b * FF * NN + (size_t)f * NN;
    const int*   __restrict__ tb = tgt + (size_t)b * NN;
    const int base  = tid * 17;
    const int cbase = g * 17;

#pragma unroll 2
    for (int k = 0; k < POINTS / 128; ++k) {
        const int n = n0 + k * 128 + g * 4;
        const int4   t4 = *reinterpret_cast<const int4*>(tb + n);
        const float4 v  = *reinterpret_cast<const float4*>(xf + n);
        priv[base + t4.x] += v.x;
        priv[base + t4.y] += v.y;
        priv[base + t4.z] += v.z;
        priv[base + t4.w] += v.w;
        if (f == 0) {
            cpriv[cbase + t4.x] += 1.f;
            cpriv[cbase + t4.y] += 1.f;
            cpriv[cbase + t4.z] += 1.f;
            cpriv[cbase + t4.w] += 1.f;
        }
    }
    __syncthreads();

    // block reduce -> per-block partial slots (plain stores, no atomics)
    float* const part = &ws[WS_PART + (size_t)(b * CHUNKS + ch) * PSLOT];
    if (tid < 128) {
        const int rf = tid >> 4, rc = tid & 15;   // slot = f*16 + c
        float s = 0.f;
#pragma unroll
        for (int gg = 0; gg < 32; ++gg) s += priv[(rf * 32 + gg) * 17 + rc];
        part[tid] = s;
    } else if (tid < 144) {
        const int rc = tid - 128;
        float s = 0.f;
#pragma unroll
        for (int gg = 0; gg < 32; ++gg) s += cpriv[gg * 17 + rc];
        part[tid] = s;
    }
}

// ---------------- Pass 2: variance term; ch==0 also dist+reg (own data) -----
__global__ __launch_bounds__(256) void k_var(const float* __restrict__ x,
                                             const int* __restrict__ tgt,
                                             float* __restrict__ ws) {
    __shared__ float sred[144];
    __shared__ float smf[CC * 12];     // float4-pair rows at stride 3 float4s
    __shared__ float sinv[CC];
    __shared__ float wsum[4];
    __shared__ int   sst[CC];

    const int tid = threadIdx.x;
    const int b   = blockIdx.y;
    const int ch  = blockIdx.x;

    // ---- prologue: derive means/inv from the 64 chunk partials ----
    if (tid < 144) {
        const float* p = &ws[WS_PART + (size_t)b * CHUNKS * PSLOT + tid];
        float s = 0.f;
#pragma unroll 16
        for (int c2 = 0; c2 < CHUNKS; ++c2) s += p[(size_t)c2 * PSLOT];
        sred[tid] = s;
    }
    if (ch == 0 && tid >= 144 && tid < 160) sst[tid - 144] = tgt[(size_t)b * NN + (tid - 144)];
    __syncthreads();
    if (tid < CC) {
        const float cnt = sred[128 + tid];
        sinv[tid] = cnt > 0.f ? 1.f / cnt : 0.f;
    }
    __syncthreads();
    if (tid < 128) {
        const int f = tid >> 4, c = tid & 15;
        smf[c * 12 + f] = sred[tid] * sinv[c];
    }
    __syncthreads();

    // ---- main loop: variance term over own chunk ----
    const float4* sm4 = reinterpret_cast<const float4*>(smf);
    const int n0 = ch * POINTS;
    const float* __restrict__ xb = x + (size_t)b * FF * NN;
    const int*   __restrict__ tb = tgt + (size_t)b * NN;

    float acc = 0.f;
#pragma unroll
    for (int it = 0; it < 2; ++it) {
        const int n = n0 + tid * 4 + it * 1024;
        const int4 t4 = *reinterpret_cast<const int4*>(tb + n);
        const float4 A0 = sm4[3 * t4.x], B0 = sm4[3 * t4.x + 1];
        const float4 A1 = sm4[3 * t4.y], B1 = sm4[3 * t4.y + 1];
        const float4 A2 = sm4[3 * t4.z], B2 = sm4[3 * t4.z + 1];
        const float4 A3 = sm4[3 * t4.w], B3 = sm4[3 * t4.w + 1];
        float s0, s1, s2, s3;
        {
            const float4 v = *reinterpret_cast<const float4*>(xb + 0 * NN + n);
            s0 = fabsf(v.x - A0.x); s1 = fabsf(v.y - A1.x);
            s2 = fabsf(v.z - A2.x); s3 = fabsf(v.w - A3.x);
        }
        {
            const float4 v = *reinterpret_cast<const float4*>(xb + 1 * NN + n);
            s0 += fabsf(v.x - A0.y); s1 += fabsf(v.y - A1.y);
            s2 += fabsf(v.z - A2.y); s3 += fabsf(v.w - A3.y);
        }
        {
            const float4 v = *reinterpret_cast<const float4*>(xb + 2 * NN + n);
            s0 += fabsf(v.x - A0.z); s1 += fabsf(v.y - A1.z);
            s2 += fabsf(v.z - A2.z); s3 += fabsf(v.w - A3.z);
        }
        {
            const float4 v = *reinterpret_cast<const float4*>(xb + 3 * NN + n);
            s0 += fabsf(v.x - A0.w); s1 += fabsf(v.y - A1.w);
            s2 += fabsf(v.z - A2.w); s3 += fabsf(v.w - A3.w);
        }
        {
            const float4 v = *reinterpret_cast<const float4*>(xb + 4 * NN + n);
            s0 += fabsf(v.x - B0.x); s1 += fabsf(v.y - B1.x);
            s2 += fabsf(v.z - B2.x); s3 += fabsf(v.w - B3.x);
        }
        {
            const float4 v = *reinterpret_cast<const float4*>(xb + 5 * NN + n);
            s0 += fabsf(v.x - B0.y); s1 += fabsf(v.y - B1.y);
            s2 += fabsf(v.z - B2.y); s3 += fabsf(v.w - B3.y);
        }
        {
            const float4 v = *reinterpret_cast<const float4*>(xb + 6 * NN + n);
            s0 += fabsf(v.x - B0.z); s1 += fabsf(v.y - B1.z);
            s2 += fabsf(v.z - B2.z); s3 += fabsf(v.w - B3.z);
        }
        {
            const float4 v = *reinterpret_cast<const float4*>(xb + 7 * NN + n);
            s0 += fabsf(v.x - B0.w); s1 += fabsf(v.y - B1.w);
            s2 += fabsf(v.z - B2.w); s3 += fabsf(v.w - B3.w);
        }
        float h;
        h = fmaxf(s0 - DELTA_VAR, 0.f); acc += h * h * sinv[t4.x];
        h = fmaxf(s1 - DELTA_VAR, 0.f); acc += h * h * sinv[t4.y];
        h = fmaxf(s2 - DELTA_VAR, 0.f); acc += h * h * sinv[t4.z];
        h = fmaxf(s3 - DELTA_VAR, 0.f); acc += h * h * sinv[t4.w];
    }

#pragma unroll
    for (int off = 32; off > 0; off >>= 1) acc += __shfl_down(acc, off, 64);
    if ((tid & 63) == 0) wsum[tid >> 6] = acc;
    __syncthreads();
    if (tid == 0) ws[WS_VARP + b * CHUNKS + ch] = wsum[0] + wsum[1] + wsum[2] + wsum[3];

    // ---- ch==0 only: dist + reg from OWN means (plain store, no sync) ----
    if (ch == 0 && tid < CC) {
        const int c = tid;
        float l1 = 0.f;
#pragma unroll
        for (int f = 0; f < FF; ++f) l1 += fabsf(smf[c * 12 + f]);
        const int ti = sst[c];
        float mi[FF];
#pragma unroll
        for (int f = 0; f < FF; ++f) mi[f] = smf[ti * 12 + f];
        float dsum = 0.f;
        for (int j = 0; j < CC; ++j) {
            const int tj = sst[j];
            float d = 0.f;
#pragma unroll
            for (int f = 0; f < FF; ++f) d += fabsf(mi[f] - smf[tj * 12 + f]);
            if (j != c) {
                const float h = 2.f * DELTA_DIST - d;
                if (h > 0.f) dsum += h * h;
            }
        }
        float contrib = (GAMMA / (float)(CC * BB)) * l1
                      + (BETA / (float)(CC * (CC - 1) * BB)) * dsum;
#pragma unroll
        for (int off = 8; off > 0; off >>= 1) contrib += __shfl_down(contrib, off, 64);
        if (tid == 0) ws[WS_DRG + b] = contrib;
    }
}

// ---------------- Final: pure reduce of 2048 var partials + 32 drg ----------
__global__ __launch_bounds__(256) void k_final(const float* __restrict__ ws,
                                               float* __restrict__ out) {
    __shared__ float red[4];
    const int tid = threadIdx.x;

    float v = 0.f;
#pragma unroll
    for (int i = 0; i < NBLK / 256; ++i) v += ws[WS_VARP + i * 256 + tid];
    float val = (ALPHA / (float)BB) * v;
    if (tid < BB) val += ws[WS_DRG + tid];

#pragma unroll
    for (int off = 32; off > 0; off >>= 1) val += __shfl_down(val, off, 64);
    if ((tid & 63) == 0) red[tid >> 6] = val;
    __syncthreads();
    if (tid == 0) out[0] = red[0] + red[1] + red[2] + red[3];
}

extern "C" void kernel_launch(void* const* d_in, const int* in_sizes, int n_in,
                              void* d_out, int out_size, void* d_ws, size_t ws_size,
                              hipStream_t stream) {
    const float* x  = (const float*)d_in[0];
    const int* tgt  = (const int*)d_in[1];
    float* out = (float*)d_out;
    float* ws  = (float*)d_ws;

    dim3 grid(CHUNKS, BB);
    k_sums<<<grid, 256, 0, stream>>>(x, tgt, ws);
    k_var <<<grid, 256, 0, stream>>>(x, tgt, ws);
    k_final<<<1, 256, 0, stream>>>(ws, out);
}